// Round 2
// baseline (171.489 us; speedup 1.0000x reference)
//
#include <hip/hip_runtime.h>

#define T_SEQ 2048
#define NH 4
#define DH 64

typedef __bf16 bf16x8 __attribute__((ext_vector_type(8)));
typedef float f32x4 __attribute__((ext_vector_type(4)));
typedef unsigned short u16x8 __attribute__((ext_vector_type(8)));

__device__ __forceinline__ unsigned short f2bf_rne(float x) {
  unsigned int u = __builtin_bit_cast(unsigned int, x);
  u += 0x7fffu + ((u >> 16) & 1u);
  return (unsigned short)(u >> 16);
}
__device__ __forceinline__ float bf2f(unsigned short s) {
  unsigned int u = ((unsigned int)s) << 16;
  return __builtin_bit_cast(float, u);
}

// ---------------------------------------------------------------------------
// prep_w: transpose + hi/lo split W (256x256 f32) -> WtHi/WtLo [n][k] bf16.
// Lives in the head of d_out; consumed by wh_gemm before attn overwrites.
// ---------------------------------------------------------------------------
__global__ void prep_w(const float* __restrict__ W,
                       unsigned short* __restrict__ WtHi,
                       unsigned short* __restrict__ WtLo) {
  __shared__ float ls[32][65];
  const int tid = threadIdx.x;
  const int k0 = (blockIdx.x >> 2) * 32;
  const int n0 = (blockIdx.x & 3) * 64;
#pragma unroll
  for (int i = 0; i < 8; i++) {
    int e = i * 256 + tid;
    int r = e >> 6, c = e & 63;
    ls[r][c] = W[(k0 + r) * 256 + n0 + c];
  }
  __syncthreads();
  const int n = tid & 63;
  const int part = tid >> 6;
  u16x8 vh, vl;
#pragma unroll
  for (int j = 0; j < 8; j++) {
    float w = ls[part * 8 + j][n];
    unsigned short h16 = f2bf_rne(w);
    vh[j] = h16;
    vl[j] = f2bf_rne(w - bf2f(h16));
  }
  size_t dst = (size_t)(n0 + n) * 256 + k0 + part * 8;
  *(u16x8*)&WtHi[dst] = vh;
  *(u16x8*)&WtLo[dst] = vl;
}

// ---------------------------------------------------------------------------
// wh_gemm: Wh = h @ W via split-bf16 MFMA (hi*hi + lo*hi + hi*lo ~ fp32 exact).
// Epilogue via padded LDS transpose -> all-b128 global stores of:
//   Kb[bh][t][d] = bf16(Wh * sqrt(log2e/8))   (Q and K)
//   Vt[bh][d][t] = bf16(Wh)                   (PV B-operand layout)
// ---------------------------------------------------------------------------
__global__ __launch_bounds__(256, 2) void wh_gemm(
    const float* __restrict__ h,
    const unsigned short* __restrict__ WtHi,
    const unsigned short* __restrict__ WtLo,
    unsigned short* __restrict__ Kb, unsigned short* __restrict__ Vt) {
  __shared__ __align__(16) unsigned short ktile[32][264];  // [t][n], stride 264 keeps b128 align
  __shared__ __align__(16) unsigned short vtile[256][40];  // [n][t], stride 40 = 80B (aligned, bank-spread)
  const int tid = threadIdx.x;
  const int wave = tid >> 6, lane = tid & 63, l15 = lane & 15, quad = lane >> 4;
  const int m0b = blockIdx.x * 32;
  const int m0 = m0b + (wave & 1) * 16;
  const int n0w = (wave >> 1) * 128;
  f32x4 acc[8];
#pragma unroll
  for (int nt = 0; nt < 8; nt++) acc[nt] = (f32x4){0.f, 0.f, 0.f, 0.f};

  for (int kc = 0; kc < 8; kc++) {
    const float4* hp = (const float4*)&h[(size_t)(m0 + l15) * 256 + kc * 32 + quad * 8];
    float4 a0 = hp[0], a1 = hp[1];
    float xs[8] = {a0.x, a0.y, a0.z, a0.w, a1.x, a1.y, a1.z, a1.w};
    u16x8 ah, al;
#pragma unroll
    for (int j = 0; j < 8; j++) {
      unsigned short h16 = f2bf_rne(xs[j]);
      ah[j] = h16;
      al[j] = f2bf_rne(xs[j] - bf2f(h16));
    }
    bf16x8 ahi = __builtin_bit_cast(bf16x8, ah);
    bf16x8 alo = __builtin_bit_cast(bf16x8, al);
#pragma unroll
    for (int nt = 0; nt < 8; nt++) {
      size_t wb = (size_t)(n0w + nt * 16 + l15) * 256 + kc * 32 + quad * 8;
      bf16x8 bhi = *(const bf16x8*)&WtHi[wb];
      bf16x8 blo = *(const bf16x8*)&WtLo[wb];
      acc[nt] = __builtin_amdgcn_mfma_f32_16x16x32_bf16(ahi, bhi, acc[nt], 0, 0, 0);
      acc[nt] = __builtin_amdgcn_mfma_f32_16x16x32_bf16(alo, bhi, acc[nt], 0, 0, 0);
      acc[nt] = __builtin_amdgcn_mfma_f32_16x16x32_bf16(ahi, blo, acc[nt], 0, 0, 0);
    }
  }
  const float s1 = 0.424664717f;  // sqrt(log2(e)/8)
  const int tl = (wave & 1) * 16 + quad * 4;
#pragma unroll
  for (int nt = 0; nt < 8; nt++) {
    int n = n0w + nt * 16 + l15;
#pragma unroll
    for (int r = 0; r < 4; r++) {
      float v = acc[nt][r];
      ktile[tl + r][n] = f2bf_rne(v * s1);
      vtile[n][tl + r] = f2bf_rne(v);
    }
  }
  __syncthreads();
  {  // Kb out: thread -> (t row, 32-col segment); 4 x b128 stores
    int t = tid >> 3, seg = tid & 7;
    int m = m0b + t, b = m >> 11, tt = m & 2047;
    int head = seg >> 1, d0 = (seg & 1) * 32;
    unsigned short* dst = &Kb[((size_t)(b * NH + head) * T_SEQ + tt) * DH + d0];
#pragma unroll
    for (int q = 0; q < 4; q++)
      *(u16x8*)&dst[q * 8] = *(const u16x8*)&ktile[t][seg * 32 + q * 8];
  }
  {  // Vt out: thread = n row; 4 x b128 stores of 32 t's
    int n = tid, head = n >> 6, d = n & 63;
    int b = m0b >> 11, t0 = m0b & 2047;
    unsigned short* dst = &Vt[((size_t)(b * NH + head) * DH + d) * T_SEQ + t0];
#pragma unroll
    for (int q = 0; q < 4; q++)
      *(u16x8*)&dst[q * 8] = *(const u16x8*)&vtile[n][q * 8];
  }
}

// ---------------------------------------------------------------------------
// attn v2: S^T formulation, zero block-level barriers, all frags b128.
//   Per block: one bh, 256 q-rows; per wave 64 q-rows, full 2048-key sweep.
//   S^T = K*Q^T: A = K-rows (global b128), B = Q-rows (regs). C-layout gives
//   4 consecutive KEYS per reg quartet -> P packs to b64 LDS writes; PV
//   A-frag reads back b128. V B-frags stream from Vt (global b128).
// ---------------------------------------------------------------------------
struct Frag {
  bf16x8 k[2][2];
  bf16x8 v[4];
};

__device__ __forceinline__ void load_frags(Frag& f, const unsigned short* Kbh,
                                           const unsigned short* Vbh, int s0,
                                           int l15, int quad) {
#pragma unroll
  for (int mt = 0; mt < 2; mt++)
#pragma unroll
    for (int kc = 0; kc < 2; kc++)
      f.k[mt][kc] = *(const bf16x8*)&Kbh[(size_t)(s0 + mt * 16 + l15) * DH + kc * 32 + quad * 8];
#pragma unroll
  for (int dt = 0; dt < 4; dt++)
    f.v[dt] = *(const bf16x8*)&Vbh[(size_t)(dt * 16 + l15) * T_SEQ + s0 + quad * 8];
}

__device__ __forceinline__ void step(const Frag& f, const bf16x8 bq[4][2],
                                     f32x4 o[4][4], float* lsum,
                                     unsigned short* Pw, int l15, int quad) {
  f32x4 s[2][4];
#pragma unroll
  for (int mt = 0; mt < 2; mt++)
#pragma unroll
    for (int nt = 0; nt < 4; nt++) {
      f32x4 c = {0.f, 0.f, 0.f, 0.f};
      c = __builtin_amdgcn_mfma_f32_16x16x32_bf16(f.k[mt][0], bq[nt][0], c, 0, 0, 0);
      c = __builtin_amdgcn_mfma_f32_16x16x32_bf16(f.k[mt][1], bq[nt][1], c, 0, 0, 0);
      s[mt][nt] = c;
    }
#pragma unroll
  for (int mt = 0; mt < 2; mt++)
#pragma unroll
    for (int nt = 0; nt < 4; nt++) {
      float e0, e1, e2, e3;
      {
        float v0 = s[mt][nt][0], v1 = s[mt][nt][1];
        float v2 = s[mt][nt][2], v3 = s[mt][nt][3];
        e0 = __builtin_amdgcn_exp2f(fmaxf(v0, 0.2f * v0));
        e1 = __builtin_amdgcn_exp2f(fmaxf(v1, 0.2f * v1));
        e2 = __builtin_amdgcn_exp2f(fmaxf(v2, 0.2f * v2));
        e3 = __builtin_amdgcn_exp2f(fmaxf(v3, 0.2f * v3));
      }
      lsum[nt] += (e0 + e1) + (e2 + e3);
      uint2 pk;
      pk.x = (__builtin_bit_cast(unsigned int, e1) & 0xffff0000u) |
             (__builtin_bit_cast(unsigned int, e0) >> 16);
      pk.y = (__builtin_bit_cast(unsigned int, e3) & 0xffff0000u) |
             (__builtin_bit_cast(unsigned int, e2) >> 16);
      *(uint2*)&Pw[(nt * 16 + l15) * 40 + mt * 16 + quad * 4] = pk;
    }
  __builtin_amdgcn_s_waitcnt(0xC07F);  // lgkmcnt(0): wave-local P round-trip
#pragma unroll
  for (int mt = 0; mt < 4; mt++) {
    bf16x8 pa = *(const bf16x8*)&Pw[(mt * 16 + l15) * 40 + quad * 8];
#pragma unroll
    for (int dt = 0; dt < 4; dt++)
      o[mt][dt] = __builtin_amdgcn_mfma_f32_16x16x32_bf16(pa, f.v[dt], o[mt][dt], 0, 0, 0);
  }
}

__global__ __launch_bounds__(256, 1) void attn(
    const unsigned short* __restrict__ Kb, const unsigned short* __restrict__ Vt,
    float* __restrict__ out) {
  __shared__ __align__(16) unsigned short Pw_all[4][64 * 40];
  __shared__ float inv_lds[4][64];
  const int tid = threadIdx.x, wave = tid >> 6, lane = tid & 63;
  const int l15 = lane & 15, quad = lane >> 4;
  const int bh = blockIdx.x & 31;   // same-bh blocks share an XCD (%8 L2 locality)
  const int qt = blockIdx.x >> 5;
  const int q0 = qt * 256 + wave * 64;
  const unsigned short* Kbh = Kb + (size_t)bh * T_SEQ * DH;
  const unsigned short* Vbh = Vt + (size_t)bh * DH * T_SEQ;
  unsigned short* Pw = Pw_all[wave];

  bf16x8 bq[4][2];
#pragma unroll
  for (int nt = 0; nt < 4; nt++)
#pragma unroll
    for (int kc = 0; kc < 2; kc++)
      bq[nt][kc] = *(const bf16x8*)&Kbh[(size_t)(q0 + nt * 16 + l15) * DH + kc * 32 + quad * 8];

  f32x4 o[4][4];
  float lsum[4] = {0.f, 0.f, 0.f, 0.f};
#pragma unroll
  for (int mt = 0; mt < 4; mt++)
#pragma unroll
    for (int dt = 0; dt < 4; dt++) o[mt][dt] = (f32x4){0.f, 0.f, 0.f, 0.f};

  Frag fa, fb;
  load_frags(fa, Kbh, Vbh, 0, l15, quad);
  for (int it = 0; it < 64; it += 2) {
    load_frags(fb, Kbh, Vbh, (it + 1) * 32, l15, quad);  // prefetch
    step(fa, bq, o, lsum, Pw, l15, quad);
    load_frags(fa, Kbh, Vbh, (it + 2 < 64) ? (it + 2) * 32 : 0, l15, quad);
    step(fb, bq, o, lsum, Pw, l15, quad);
  }

  // l reduction: quads hold disjoint key subsets -> xor 16, 32
#pragma unroll
  for (int nt = 0; nt < 4; nt++) {
    float l = lsum[nt];
    l += __shfl_xor(l, 16, 64);
    l += __shfl_xor(l, 32, 64);
    if (quad == 0) inv_lds[wave][nt * 16 + l15] = 1.0f / l;
  }
  __builtin_amdgcn_s_waitcnt(0xC07F);

  const int b = bh >> 2, head = bh & 3;
#pragma unroll
  for (int mt = 0; mt < 4; mt++) {
#pragma unroll
    for (int r = 0; r < 4; r++) {
      float iv = inv_lds[wave][mt * 16 + quad * 4 + r];
      int qg = q0 + mt * 16 + quad * 4 + r;
      float* dst = &out[((size_t)b * T_SEQ + qg) * 256 + head * DH];
#pragma unroll
      for (int dt = 0; dt < 4; dt++) dst[dt * 16 + l15] = o[mt][dt][r] * iv;
    }
  }
}

extern "C" void kernel_launch(void* const* d_in, const int* in_sizes, int n_in,
                              void* d_out, int out_size, void* d_ws, size_t ws_size,
                              hipStream_t stream) {
  const float* h = (const float*)d_in[0];
  const float* W = (const float*)d_in[1];
  float* out = (float*)d_out;
  unsigned short* Kb = (unsigned short*)d_ws;                 // 8 MB
  unsigned short* Vt = Kb + (size_t)32 * T_SEQ * DH;          // 8 MB
  // Wt tables live in the head of d_out: written by prep_w, read by wh_gemm,
  // fully overwritten by attn's output stores afterwards (stream-ordered).
  unsigned short* WtHi = (unsigned short*)out;
  unsigned short* WtLo = WtHi + 65536;
  prep_w<<<32, 256, 0, stream>>>(W, WtHi, WtLo);
  wh_gemm<<<512, 256, 0, stream>>>(h, WtHi, WtLo, Kb, Vt);
  attn<<<256, 256, 0, stream>>>(Kb, Vt, out);
}